// Round 1
// baseline (864.424 us; speedup 1.0000x reference)
//
#include <hip/hip_runtime.h>
#include <hip/hip_bf16.h>

// ---------------------------------------------------------------------------
// EfficientViT block (LiteMLA + MBConv), B=16, C=256, H=W=32, fp32.
// Round 0: correctness-first fp32 implementation.
//   K1 gemm qkv      : qkv = Wqkv @ x            (768x256 @ 256x1024, per b)
//   K2 dwconv 5x5    : dw  = depthwise(qkv)
//   K3 grouped 1x1   : agg = gconv(dw)           (24 groups of 32->32)
//   K4a kv           : kv[b,h] = relu(K)^T [V;1] (32x33 per (b,head))
//   K4b out          : attn = (relu(Q) kv) normalize
//   K5 gemm proj     : y1 = BN(Wproj @ attn) + x
//   K6 gemm mb1      : h1 = hswish(Wmb1 @ y1 + b1)
//   K7 dwconv 3x3    : h2 = hswish(depthwise(h1) + bdw)
//   K8 gemm mb2      : out = BN(Wmb2 @ h2) + y1
// Workspace layout (floats), with liveness aliasing; total 42,213,376 floats
// = 168.9 MB:
//   [0        , 12582912) qkv      (alias: h1 = [0,16777216))
//   [12582912 , 25165824) dw       (alias: attn = [12582912,20971520);
//                                   h2 = [16777216,33554432))
//   [25165824 , 37748736) agg
//   [37748736 , 38019072) kv
//   [38019072 , 42213376) y1
// ---------------------------------------------------------------------------

#define HW 1024
#define EPSV 1e-5f

__device__ __forceinline__ float hswish(float v) {
    return v * fminf(fmaxf(v + 3.f, 0.f), 6.f) * (1.f / 6.f);
}

// ---------------- GEMM: C[b][m][n] = sum_k A[m][k] * B[b][k][n] -------------
// EPI 0: plain   EPI 1: +bias, hardswish   EPI 2: *scale+bias+residual
template<int EPI>
__global__ __launch_bounds__(256) void gemm_k(
    const float* __restrict__ A, const float* __restrict__ Bm,
    float* __restrict__ Cm, const float* __restrict__ s1,
    const float* __restrict__ s2, const float* __restrict__ R,
    int M, int N, int K)
{
    const int b = blockIdx.z;
    const float* Bp = Bm + (size_t)b * K * N;
    float*       Cp = Cm + (size_t)b * M * N;
    const float* Rp = (EPI == 2) ? R + (size_t)b * M * N : nullptr;
    const int n0 = blockIdx.x * 64;
    const int m0 = blockIdx.y * 64;
    const int t  = threadIdx.x;
    const int tx = t & 15, ty = t >> 4;

    __shared__ float As[16][65];   // [kk][mm], padded: conflict-free staging
    __shared__ float Bs[16][64];   // [kk][nn]

    float acc[4][4] = {};
    for (int k0 = 0; k0 < K; k0 += 16) {
        #pragma unroll
        for (int u = 0; u < 4; ++u) {          // A tile 64m x 16k
            int idx = t + u * 256;
            int mm = idx >> 4, kk = idx & 15;
            As[kk][mm] = A[(size_t)(m0 + mm) * K + k0 + kk];
        }
        #pragma unroll
        for (int u = 0; u < 4; ++u) {          // B tile 16k x 64n
            int idx = t + u * 256;
            int kk = idx >> 6, nn = idx & 63;
            Bs[kk][nn] = Bp[(size_t)(k0 + kk) * N + n0 + nn];
        }
        __syncthreads();
        #pragma unroll
        for (int kk = 0; kk < 16; ++kk) {
            float a[4], bb[4];
            #pragma unroll
            for (int i = 0; i < 4; ++i) a[i] = As[kk][ty * 4 + i];
            #pragma unroll
            for (int j = 0; j < 4; ++j) bb[j] = Bs[kk][tx * 4 + j];
            #pragma unroll
            for (int i = 0; i < 4; ++i)
                #pragma unroll
                for (int j = 0; j < 4; ++j)
                    acc[i][j] += a[i] * bb[j];
        }
        __syncthreads();
    }
    #pragma unroll
    for (int i = 0; i < 4; ++i) {
        const int row = m0 + ty * 4 + i;
        float p1 = 0.f, p2 = 0.f;
        if (EPI == 1) p1 = s1[row];
        if (EPI == 2) { p1 = s1[row]; p2 = s2[row]; }
        #pragma unroll
        for (int j = 0; j < 4; ++j) {
            const int col = n0 + tx * 4 + j;
            const size_t off = (size_t)row * N + col;
            float v = acc[i][j];
            if (EPI == 1) { v += p1; v = hswish(v); }
            if (EPI == 2) { v = v * p1 + p2 + Rp[off]; }
            Cp[off] = v;
        }
    }
}

// ---------------- depthwise conv KSxKS, pad PAD, optional bias+hardswish ----
template<int KS, int PAD, int NCH, bool HS>
__global__ __launch_bounds__(256) void dwconv_k(
    const float* __restrict__ in, const float* __restrict__ w,
    const float* __restrict__ bias, float* __restrict__ out)
{
    constexpr int T = 32 + 2 * PAD;
    __shared__ float tile[T * T];
    const int plane = blockIdx.x;            // b*NCH + c
    const int c = plane % NCH;
    const float* ip = in + (size_t)plane * HW;
    const int t = threadIdx.x;
    for (int idx = t; idx < T * T; idx += 256) {
        int r = idx / T, cc = idx % T;
        int gr = r - PAD, gc = cc - PAD;
        float v = 0.f;
        if ((unsigned)gr < 32u && (unsigned)gc < 32u) v = ip[gr * 32 + gc];
        tile[idx] = v;
    }
    float wl[KS * KS];
    #pragma unroll
    for (int u = 0; u < KS * KS; ++u) wl[u] = w[c * KS * KS + u];
    const float bv = HS ? bias[c] : 0.f;
    __syncthreads();
    #pragma unroll
    for (int pj = 0; pj < 4; ++pj) {
        const int px = t + pj * 256;
        const int pr = px >> 5, pc = px & 31;
        float s = bv;
        #pragma unroll
        for (int dr = 0; dr < KS; ++dr)
            #pragma unroll
            for (int dc = 0; dc < KS; ++dc)
                s += tile[(pr + dr) * T + pc + dc] * wl[dr * KS + dc];
        if (HS) s = hswish(s);
        out[(size_t)plane * HW + px] = s;
    }
}

// ---------------- grouped 1x1: agg[b][g*32+oc][n] = sum_i w[..][i]*dw[..] ---
__global__ __launch_bounds__(256) void gconv_k(
    const float* __restrict__ dw, const float* __restrict__ wpw,
    float* __restrict__ agg)
{
    const int gx = blockIdx.x;               // g*4 + ntile
    const int g = gx >> 2, nt = gx & 3;
    const int b = blockIdx.y;
    const int n0 = nt * 256;
    const int t = threadIdx.x;
    __shared__ float dt[32][256];
    __shared__ float wl[32 * 32];
    const float* dp = dw + ((size_t)b * 768 + g * 32) * HW + n0;
    for (int idx = t; idx < 32 * 256; idx += 256) {
        int i = idx >> 8, nn = idx & 255;
        dt[i][nn] = dp[(size_t)i * HW + nn];
    }
    for (int idx = t; idx < 1024; idx += 256) wl[idx] = wpw[g * 1024 + idx];
    __syncthreads();
    float acc[32] = {};
    #pragma unroll
    for (int i = 0; i < 32; ++i) {
        const float d = dt[i][t];
        #pragma unroll
        for (int oc = 0; oc < 32; ++oc) acc[oc] += wl[oc * 32 + i] * d;
    }
    float* ap = agg + ((size_t)b * 768 + g * 32) * HW + n0;
    #pragma unroll
    for (int oc = 0; oc < 32; ++oc) ap[(size_t)oc * HW + t] = acc[oc];
}

// ---------------- kv[b,h][d][e] = sum_n relu(k[n][d]) * v~[n][e] ------------
// v~[n][e] = v[n][e] for e<32, 1.0 for e==32
__global__ __launch_bounds__(256) void kv_k(
    const float* __restrict__ qkv, const float* __restrict__ agg,
    float* __restrict__ kvb)
{
    const int bh = blockIdx.x;               // b*16 + h
    const int b = bh >> 4, h = bh & 15;
    const float* src = (h < 8) ? qkv + ((size_t)b * 768 + h * 96) * HW
                               : agg + ((size_t)b * 768 + (h - 8) * 96) * HW;
    const float* kp = src + 32 * HW;
    const float* vp = src + 64 * HW;
    const int t = threadIdx.x;
    __shared__ float ks[32 * 129];           // stride 129: conflict-free
    __shared__ float vs[33 * 129];           // row 32 == ones column

    if (t < 128) vs[32 * 129 + t] = 1.f;
    int dd[5], ee[5];
    bool vld[5];
    #pragma unroll
    for (int j = 0; j < 5; ++j) {
        int p = t + j * 256;
        vld[j] = p < 1056;
        dd[j] = vld[j] ? p / 33 : 0;
        ee[j] = vld[j] ? p % 33 : 0;
    }
    float acc[5] = {};
    for (int n0 = 0; n0 < HW; n0 += 128) {
        for (int idx = t; idx < 4096; idx += 256) {
            int row = idx >> 7, col = idx & 127;
            ks[row * 129 + col] = fmaxf(kp[(size_t)row * HW + n0 + col], 0.f);
            vs[row * 129 + col] = vp[(size_t)row * HW + n0 + col];
        }
        __syncthreads();
        #pragma unroll 4
        for (int nn = 0; nn < 128; ++nn) {
            #pragma unroll
            for (int j = 0; j < 5; ++j) {
                if (vld[j])
                    acc[j] += ks[dd[j] * 129 + nn] * vs[ee[j] * 129 + nn];
            }
        }
        __syncthreads();
    }
    #pragma unroll
    for (int j = 0; j < 5; ++j)
        if (vld[j]) kvb[(size_t)bh * 1056 + t + j * 256] = acc[j];
}

// ---------------- attn[b][h*32+e][n] = (relu(q[n]) . kv[:,e]) / denom -------
__global__ __launch_bounds__(256) void attnout_k(
    const float* __restrict__ qkv, const float* __restrict__ agg,
    const float* __restrict__ kvb, float* __restrict__ attn)
{
    const int bh = blockIdx.x;
    const int b = bh >> 4, h = bh & 15;
    const float* src = (h < 8) ? qkv + ((size_t)b * 768 + h * 96) * HW
                               : agg + ((size_t)b * 768 + (h - 8) * 96) * HW;
    const int t = threadIdx.x;
    __shared__ float kvs[1056];
    for (int idx = t; idx < 1056; idx += 256) kvs[idx] = kvb[(size_t)bh * 1056 + idx];
    __syncthreads();
    for (int jj = 0; jj < 4; ++jj) {
        const int n = t + jj * 256;
        float acc[33] = {};
        #pragma unroll 4
        for (int d = 0; d < 32; ++d) {
            const float qd = fmaxf(src[(size_t)d * HW + n], 0.f);
            #pragma unroll
            for (int e = 0; e < 33; ++e) acc[e] += qd * kvs[d * 33 + e];
        }
        const float inv = 1.f / (acc[32] + EPSV);
        float* ap = attn + ((size_t)b * 512 + h * 32) * HW + n;
        #pragma unroll
        for (int e = 0; e < 32; ++e) ap[(size_t)e * HW] = acc[e] * inv;
    }
}

// ---------------------------------------------------------------------------
extern "C" void kernel_launch(void* const* d_in, const int* in_sizes, int n_in,
                              void* d_out, int out_size, void* d_ws, size_t ws_size,
                              hipStream_t stream)
{
    const float* x        = (const float*)d_in[0];
    const float* w_qkv    = (const float*)d_in[1];
    const float* w_agg_dw = (const float*)d_in[2];
    const float* w_agg_pw = (const float*)d_in[3];
    const float* w_proj   = (const float*)d_in[4];
    const float* bnp_s    = (const float*)d_in[5];
    const float* bnp_b    = (const float*)d_in[6];
    const float* w_mb1    = (const float*)d_in[7];
    const float* b_mb1    = (const float*)d_in[8];
    const float* w_mb_dw  = (const float*)d_in[9];
    const float* b_mb_dw  = (const float*)d_in[10];
    const float* w_mb2    = (const float*)d_in[11];
    const float* bn2_s    = (const float*)d_in[12];
    const float* bn2_b    = (const float*)d_in[13];
    float* out = (float*)d_out;
    float* ws  = (float*)d_ws;

    float* qkv  = ws;                        // 12,582,912
    float* dw   = ws + 12582912;             // 12,582,912
    float* agg  = ws + 25165824;             // 12,582,912
    float* kvb  = ws + 37748736;             //    270,336
    float* y1   = ws + 38019072;             //  4,194,304
    float* attn = dw;                        // alias (dw dead after gconv)
    float* h1   = ws;                        // alias (qkv/attn dead)
    float* h2   = ws + 16777216;             // alias (dw/agg dead)

    dim3 blk(256);
    // K1: qkv = Wqkv @ x
    gemm_k<0><<<dim3(16, 12, 16), blk, 0, stream>>>(
        w_qkv, x, qkv, nullptr, nullptr, nullptr, 768, 1024, 256);
    // K2: depthwise 5x5, pad 2
    dwconv_k<5, 2, 768, false><<<dim3(16 * 768), blk, 0, stream>>>(
        qkv, w_agg_dw, nullptr, dw);
    // K3: grouped 1x1 (24 groups of 32)
    gconv_k<<<dim3(24 * 4, 16), blk, 0, stream>>>(dw, w_agg_pw, agg);
    // K4a: kv accumulation
    kv_k<<<dim3(256), blk, 0, stream>>>(qkv, agg, kvb);
    // K4b: normalized attention output
    attnout_k<<<dim3(256), blk, 0, stream>>>(qkv, agg, kvb, attn);
    // K5: y1 = BN(Wproj @ attn) + x
    gemm_k<2><<<dim3(16, 4, 16), blk, 0, stream>>>(
        w_proj, attn, y1, bnp_s, bnp_b, x, 256, 1024, 512);
    // K6: h1 = hswish(Wmb1 @ y1 + b1)
    gemm_k<1><<<dim3(16, 16, 16), blk, 0, stream>>>(
        w_mb1, y1, h1, b_mb1, nullptr, nullptr, 1024, 1024, 256);
    // K7: h2 = hswish(depthwise3x3(h1) + bdw)
    dwconv_k<3, 1, 1024, true><<<dim3(16 * 1024), blk, 0, stream>>>(
        h1, w_mb_dw, b_mb_dw, h2);
    // K8: out = BN(Wmb2 @ h2) + y1
    gemm_k<2><<<dim3(16, 4, 16), blk, 0, stream>>>(
        w_mb2, h2, out, bn2_s, bn2_b, y1, 256, 1024, 1024);
}

// Round 2
// 269.275 us; speedup vs baseline: 3.2102x; 3.2102x over previous
//
#include <hip/hip_runtime.h>
#include <hip/hip_bf16.h>

// ---------------------------------------------------------------------------
// EfficientViT block (LiteMLA + MBConv), B=16, C=256, H=W=32.
// Round 1: bf16 MFMA everywhere; kv/attn via direct-from-global MFMA.
// Pipeline:
//   P0 prep       : bf16 casts of x and the 4 GEMM weights
//   K1 gemm qkv   : qkv_b = Wqkv @ xb                 (bf16 out)
//   K2 dwconv 5x5 : dw_b  = depthwise(qkv_b)
//   K3 gconv 1x1  : agg_b = gconv(dw_b)  (24 groups of 32->32)
//   K4a kv        : kvp[bh][nc] = relu(K)^T [V;1] partials  (MFMA, no LDS)
//   K4b attn      : attn_b = normalize(relu(Q) kv)          (MFMA)
//   K5 gemm proj  : y1f/y1b = BN(Wproj @ attn) + x
//   K6 gemm mb1   : h1_b = hswish(Wmb1 @ y1b + b1)
//   K7 dwconv 3x3 : h2_b = hswish(depthwise(h1_b) + bdw)
//   K8 gemm mb2   : out = BN(Wmb2 @ h2_b) + y1f       (fp32 out)
// Workspace (byte offsets, 113.7 MB total; liveness-aliased):
//   [0        , 25165824) qkv_b          | h1_b = [0, 33554432)   (K6+)
//   [25165824 , 33554432) xb             |
//   [33554432 , 58720256) dw_b           | attn_b = [33554432, 50331648) (K4b+)
//   [58720256 , 83886080) agg_b          | h2_b = [58720256, 92274688)  (K7+)
//   [83886080 , 88211456) kvp            |
//   [92274688 ,109051904) y1f (fp32)
//   [109051904,117440512) y1b
//   [117440512,...      ) wq_b, wp_b, w1_b, w2_b (bf16 weights)
// ---------------------------------------------------------------------------

typedef unsigned short u16;
typedef __attribute__((ext_vector_type(8))) short short8;
typedef __attribute__((ext_vector_type(4))) short short4v;
typedef __attribute__((ext_vector_type(4))) float f32x4;

#define HW 1024
#define EPSV 1e-5f
#define MFMA16(a, b, c) __builtin_amdgcn_mfma_f32_16x16x32_bf16((a), (b), (c), 0, 0, 0)

__device__ __forceinline__ u16 f2bf(float f) {
    union { __hip_bfloat16 h; u16 u; } c; c.h = __float2bfloat16(f); return c.u;
}
__device__ __forceinline__ float bf2f(u16 u) {
    union { u16 u; __hip_bfloat16 h; } c; c.u = u; return __bfloat162float(c.h);
}
__device__ __forceinline__ float hswish(float v) {
    return v * fminf(fmaxf(v + 3.f, 0.f), 6.f) * (1.f / 6.f);
}

// ---------------- P0: fp32 -> bf16 casts ------------------------------------
__global__ __launch_bounds__(256) void prep_k(
    const float* __restrict__ x,  u16* __restrict__ xb,
    const float* __restrict__ wq, u16* __restrict__ wqb,
    const float* __restrict__ wp, u16* __restrict__ wpb,
    const float* __restrict__ w1, u16* __restrict__ w1b,
    const float* __restrict__ w2, u16* __restrict__ w2b)
{
    const int N0 = 4194304, N1 = 196608, N2 = 131072, N3 = 262144;
    const int total = N0 + N1 + N2 + N3 + 262144;
    for (int i = blockIdx.x * 256 + threadIdx.x; i < total; i += gridDim.x * 256) {
        int id = i;
        if (id < N0) { xb[id]  = f2bf(x[id]);  continue; } id -= N0;
        if (id < N1) { wqb[id] = f2bf(wq[id]); continue; } id -= N1;
        if (id < N2) { wpb[id] = f2bf(wp[id]); continue; } id -= N2;
        if (id < N3) { w1b[id] = f2bf(w1[id]); continue; } id -= N3;
        w2b[id] = f2bf(w2[id]);
    }
}

// ---------------- bf16 MFMA GEMM: C[b][m][n] = sum_k A[m][k]*Act[b][k][n] ---
// 128x128 tile, BK=64, 4 waves (each 64x64 = 4x4 frags of 16x16x32).
// LDS: As[row m][64 k], Bs[row n][64 k] (transposed on stage), both
// XOR-chunk-swizzled (chunk ^= row&7) on write AND read (rule 21).
// EPI 0: bf16 store   1: +bias,hswish,bf16   2: BN+res -> f32 & bf16   3: BN+res -> f32
template<int EPI>
__global__ __launch_bounds__(256) void gemm_bf(
    const u16* __restrict__ A, const u16* __restrict__ Bact,
    const float* __restrict__ s1, const float* __restrict__ s2,
    const float* __restrict__ Rres, float* __restrict__ outF,
    u16* __restrict__ outB, int M, int K)
{
    const int b  = blockIdx.z;
    const int n0 = blockIdx.x * 128;
    const int m0 = blockIdx.y * 128;
    const int t  = threadIdx.x;
    const int lr = t & 15, lg = (t >> 4) & 3;
    const int wid = t >> 6, wm = wid >> 1, wn = wid & 1;

    __shared__ u16 As[128 * 64];
    __shared__ u16 Bs[128 * 64];

    const u16* Bp = Bact + (size_t)b * K * HW;

    f32x4 zero4 = {0.f, 0.f, 0.f, 0.f};
    f32x4 acc[4][4];
    #pragma unroll
    for (int i = 0; i < 4; ++i)
        #pragma unroll
        for (int j = 0; j < 4; ++j) acc[i][j] = zero4;

    for (int k0 = 0; k0 < K; k0 += 64) {
        { // stage A (weights, bf16x8 vector loads)
            const u16* Ab = A + (size_t)m0 * K + k0;
            #pragma unroll
            for (int u = 0; u < 4; ++u) {
                int id = t + u * 256;                 // 1024 chunks
                int row = id >> 3, c = id & 7;
                short8 v = *(const short8*)(Ab + (size_t)row * K + c * 8);
                *(short8*)(&As[row * 64 + ((c ^ (row & 7)) * 8)]) = v;
            }
        }
        { // stage B transposed: Bs[n][k] from Act[k][n] (2B scalar loads)
            const u16* Bb = Bp + (size_t)k0 * HW + n0;
            int n = t & 127, kh = t >> 7;
            #pragma unroll
            for (int u = 0; u < 4; ++u) {
                int c = kh * 4 + u;
                short8 v;
                #pragma unroll
                for (int g = 0; g < 8; ++g)
                    v[g] = (short)Bb[(size_t)(c * 8 + g) * HW + n];
                *(short8*)(&Bs[n * 64 + ((c ^ (n & 7)) * 8)]) = v;
            }
        }
        __syncthreads();
        #pragma unroll
        for (int kk = 0; kk < 2; ++kk) {
            short8 a[4], bb[4];
            #pragma unroll
            for (int i = 0; i < 4; ++i) {
                int row = wm * 64 + i * 16 + lr;
                a[i] = *(const short8*)(&As[row * 64 + (((kk * 4 + lg) ^ (lr & 7)) * 8)]);
            }
            #pragma unroll
            for (int j = 0; j < 4; ++j) {
                int row = wn * 64 + j * 16 + lr;
                bb[j] = *(const short8*)(&Bs[row * 64 + (((kk * 4 + lg) ^ (lr & 7)) * 8)]);
            }
            #pragma unroll
            for (int i = 0; i < 4; ++i)
                #pragma unroll
                for (int j = 0; j < 4; ++j)
                    acc[i][j] = MFMA16(a[i], bb[j], acc[i][j]);
        }
        __syncthreads();
    }

    const size_t obase = (size_t)b * M * HW;
    #pragma unroll
    for (int i = 0; i < 4; ++i) {
        #pragma unroll
        for (int r = 0; r < 4; ++r) {
            const int grow = m0 + wm * 64 + i * 16 + lg * 4 + r;
            float p1 = 0.f, p2 = 0.f;
            if (EPI == 1) { p1 = s1[grow]; }
            if (EPI >= 2) { p1 = s1[grow]; p2 = s2[grow]; }
            #pragma unroll
            for (int j = 0; j < 4; ++j) {
                const int gcol = n0 + wn * 64 + j * 16 + lr;
                const size_t off = obase + (size_t)grow * HW + gcol;
                float v = acc[i][j][r];
                if (EPI == 0) { outB[off] = f2bf(v); }
                if (EPI == 1) { v = hswish(v + p1); outB[off] = f2bf(v); }
                if (EPI == 2) { v = v * p1 + p2 + Rres[off]; outF[off] = v; outB[off] = f2bf(v); }
                if (EPI == 3) { v = v * p1 + p2 + Rres[off]; outF[off] = v; }
            }
        }
    }
}

// ---------------- depthwise conv (bf16 io, fp32 math) -----------------------
template<int KS, int PAD, int NCH, bool HS>
__global__ __launch_bounds__(256) void dwconv_k(
    const u16* __restrict__ in, const float* __restrict__ w,
    const float* __restrict__ bias, u16* __restrict__ out)
{
    constexpr int T = 32 + 2 * PAD;
    __shared__ float tile[T * T];
    const int plane = blockIdx.x;
    const int c = plane % NCH;
    const u16* ip = in + (size_t)plane * HW;
    const int t = threadIdx.x;
    for (int idx = t; idx < T * T; idx += 256) {
        int r = idx / T, cc = idx % T;
        int gr = r - PAD, gc = cc - PAD;
        float v = 0.f;
        if ((unsigned)gr < 32u && (unsigned)gc < 32u) v = bf2f(ip[gr * 32 + gc]);
        tile[idx] = v;
    }
    float wl[KS * KS];
    #pragma unroll
    for (int u = 0; u < KS * KS; ++u) wl[u] = w[c * KS * KS + u];
    const float bv = HS ? bias[c] : 0.f;
    __syncthreads();
    #pragma unroll
    for (int pj = 0; pj < 4; ++pj) {
        const int px = t + pj * 256;
        const int pr = px >> 5, pc = px & 31;
        float s = bv;
        #pragma unroll
        for (int dr = 0; dr < KS; ++dr)
            #pragma unroll
            for (int dc = 0; dc < KS; ++dc)
                s += tile[(pr + dr) * T + pc + dc] * wl[dr * KS + dc];
        if (HS) s = hswish(s);
        out[(size_t)plane * HW + px] = f2bf(s);
    }
}

// ---------------- grouped 1x1 (24 groups of 32->32), bf16 io ----------------
__global__ __launch_bounds__(256) void gconv_k(
    const u16* __restrict__ dw, const float* __restrict__ wpw,
    u16* __restrict__ agg)
{
    const int gx = blockIdx.x;               // g*4 + ntile
    const int g = gx >> 2, nt = gx & 3;
    const int b = blockIdx.y;
    const int n0 = nt * 256;
    const int t = threadIdx.x;
    __shared__ float dt[32][256];
    __shared__ float wl[32 * 32];
    const u16* dp = dw + ((size_t)b * 768 + g * 32) * HW + n0;
    for (int idx = t; idx < 32 * 256; idx += 256) {
        int i = idx >> 8, nn = idx & 255;
        dt[i][nn] = bf2f(dp[(size_t)i * HW + nn]);
    }
    for (int idx = t; idx < 1024; idx += 256) wl[idx] = wpw[g * 1024 + idx];
    __syncthreads();
    float acc[32] = {};
    #pragma unroll
    for (int i = 0; i < 32; ++i) {
        const float d = dt[i][t];
        #pragma unroll
        for (int oc = 0; oc < 32; ++oc) acc[oc] += wl[oc * 32 + i] * d;
    }
    u16* ap = agg + ((size_t)b * 768 + g * 32) * HW + n0;
    #pragma unroll
    for (int oc = 0; oc < 32; ++oc) ap[(size_t)oc * HW + t] = f2bf(acc[oc]);
}

// ---------------- K4a: kv partials via MFMA, zero LDS -----------------------
// kv[d][e] = sum_n relu(K[d][n]) * V[e][n]  (+ ones column e=32).
// A-frag: K[d][n] contiguous in n; B-frag: V[e][n] contiguous in n.
// One wave per (b,h,n-chunk of 256). kvp layout [bh][nc][1056].
__global__ __launch_bounds__(64) void kv_k(
    const u16* __restrict__ qkvb, const u16* __restrict__ aggb,
    float* __restrict__ kvp)
{
    const int blk = blockIdx.x;              // bh*4 + nc
    const int bh = blk >> 2, nc = blk & 3;
    const int b = bh >> 4, h = bh & 15;
    const u16* src = (h < 8) ? qkvb + ((size_t)b * 768 + h * 96) * HW
                             : aggb + ((size_t)b * 768 + (h - 8) * 96) * HW;
    const u16* kp = src + 32 * HW + nc * 256;
    const u16* vp = src + 64 * HW + nc * 256;
    const int l = threadIdx.x;
    const int lr = l & 15, lg = l >> 4;

    f32x4 zero4 = {0.f, 0.f, 0.f, 0.f};
    f32x4 acc[2][3];
    #pragma unroll
    for (int i = 0; i < 2; ++i)
        #pragma unroll
        for (int j = 0; j < 3; ++j) acc[i][j] = zero4;

    short8 bones;
    #pragma unroll
    for (int g = 0; g < 8; ++g) bones[g] = (lr == 0) ? (short)0x3F80 : (short)0;

    for (int ks = 0; ks < 8; ++ks) {
        const int kn = ks * 32 + lg * 8;
        short8 a0 = *(const short8*)(kp + (size_t)lr * HW + kn);
        short8 a1 = *(const short8*)(kp + (size_t)(16 + lr) * HW + kn);
        #pragma unroll
        for (int g = 0; g < 8; ++g) {     // relu on bf16 bits
            if (((u16)a0[g]) & 0x8000) a0[g] = 0;
            if (((u16)a1[g]) & 0x8000) a1[g] = 0;
        }
        short8 b0 = *(const short8*)(vp + (size_t)lr * HW + kn);
        short8 b1 = *(const short8*)(vp + (size_t)(16 + lr) * HW + kn);
        acc[0][0] = MFMA16(a0, b0, acc[0][0]);
        acc[0][1] = MFMA16(a0, b1, acc[0][1]);
        acc[0][2] = MFMA16(a0, bones, acc[0][2]);
        acc[1][0] = MFMA16(a1, b0, acc[1][0]);
        acc[1][1] = MFMA16(a1, b1, acc[1][1]);
        acc[1][2] = MFMA16(a1, bones, acc[1][2]);
    }
    float* dst = kvp + (size_t)blk * 1056;
    #pragma unroll
    for (int dt = 0; dt < 2; ++dt)
        #pragma unroll
        for (int et = 0; et < 3; ++et)
            #pragma unroll
            for (int r = 0; r < 4; ++r) {
                const int d = dt * 16 + lg * 4 + r;
                const int e = et * 16 + lr;
                if (et < 2 || lr == 0) dst[d * 33 + e] = acc[dt][et][r];
            }
}

// ---------------- K4b: attn = normalize(relu(Q) @ kv) via MFMA --------------
// A = Q^T (staged in LDS, rows padded to 40 u16); B = kv (bf16 reg frags).
// Block = (bh, n-chunk of 256), 4 waves x 64 n each.
__global__ __launch_bounds__(256) void attn_k(
    const u16* __restrict__ qkvb, const u16* __restrict__ aggb,
    const float* __restrict__ kvp, u16* __restrict__ attnb)
{
    const int blk = blockIdx.x;
    const int bh = blk >> 2, nc = blk & 3;
    const int b = bh >> 4, h = bh & 15;
    const u16* qp = (h < 8) ? qkvb + ((size_t)b * 768 + h * 96) * HW
                            : aggb + ((size_t)b * 768 + (h - 8) * 96) * HW;
    __shared__ u16 qs[256 * 40];
    const int t = threadIdx.x;
    #pragma unroll 4
    for (int u = 0; u < 32; ++u) {           // stage Q^T with relu
        int id = t + u * 256;                // 8192 elems
        int d = id >> 8, n = id & 255;
        u16 q = qp[(size_t)d * HW + nc * 256 + n];
        if (q & 0x8000) q = 0;
        qs[n * 40 + d] = q;
    }
    const int lr = t & 15, lg = (t >> 4) & 3, w = t >> 6;

    short8 bf[3];                            // kv as B-frags (sum 4 partials)
    const float* kb = kvp + (size_t)bh * 4 * 1056;
    #pragma unroll
    for (int et = 0; et < 3; ++et)
        #pragma unroll
        for (int j = 0; j < 8; ++j) {
            const int d = lg * 8 + j, e = et * 16 + lr;
            float s = 0.f;
            if (e <= 32) {
                #pragma unroll
                for (int c = 0; c < 4; ++c) s += kb[c * 1056 + d * 33 + e];
            }
            bf[et][j] = (short)f2bf(s);
        }
    __syncthreads();

    f32x4 zero4 = {0.f, 0.f, 0.f, 0.f};
    f32x4 acc[4][3];
    #pragma unroll
    for (int i = 0; i < 4; ++i) {
        const int row = w * 64 + i * 16 + lr;
        short8 a = *(const short8*)(&qs[row * 40 + lg * 8]);
        #pragma unroll
        for (int et = 0; et < 3; ++et) acc[i][et] = MFMA16(a, bf[et], zero4);
    }

    u16* ap = attnb + (size_t)b * 512 * HW + (size_t)h * 32 * HW;
    #pragma unroll
    for (int i = 0; i < 4; ++i) {
        float inv[4];
        #pragma unroll
        for (int r = 0; r < 4; ++r) {
            const float den = __shfl(acc[i][2][r], t & 48, 64);
            inv[r] = 1.f / (den + EPSV);
        }
        const int nbase = nc * 256 + w * 64 + i * 16 + lg * 4;
        #pragma unroll
        for (int et = 0; et < 2; ++et) {
            const int e = et * 16 + lr;
            short4v o;
            #pragma unroll
            for (int r = 0; r < 4; ++r) o[r] = (short)f2bf(acc[i][et][r] * inv[r]);
            *(short4v*)(ap + (size_t)e * HW + nbase) = o;
        }
    }
}

// ---------------------------------------------------------------------------
extern "C" void kernel_launch(void* const* d_in, const int* in_sizes, int n_in,
                              void* d_out, int out_size, void* d_ws, size_t ws_size,
                              hipStream_t stream)
{
    const float* x        = (const float*)d_in[0];
    const float* w_qkv    = (const float*)d_in[1];
    const float* w_agg_dw = (const float*)d_in[2];
    const float* w_agg_pw = (const float*)d_in[3];
    const float* w_proj   = (const float*)d_in[4];
    const float* bnp_s    = (const float*)d_in[5];
    const float* bnp_b    = (const float*)d_in[6];
    const float* w_mb1    = (const float*)d_in[7];
    const float* b_mb1    = (const float*)d_in[8];
    const float* w_mb_dw  = (const float*)d_in[9];
    const float* b_mb_dw  = (const float*)d_in[10];
    const float* w_mb2    = (const float*)d_in[11];
    const float* bn2_s    = (const float*)d_in[12];
    const float* bn2_b    = (const float*)d_in[13];
    float* out = (float*)d_out;
    char*  W   = (char*)d_ws;

    u16*   qkvb  = (u16*)(W + 0);
    u16*   xb    = (u16*)(W + 25165824);
    u16*   dwb   = (u16*)(W + 33554432);
    u16*   aggb  = (u16*)(W + 58720256);
    float* kvp   = (float*)(W + 83886080);
    u16*   attnb = (u16*)(W + 33554432);     // alias: dwb dead after gconv
    u16*   h1b   = (u16*)(W + 0);            // alias: qkvb+xb dead after attn
    u16*   h2b   = (u16*)(W + 58720256);     // alias: aggb+kvp dead after attn
    float* y1f   = (float*)(W + 92274688);
    u16*   y1b   = (u16*)(W + 109051904);
    u16*   wqb   = (u16*)(W + 117440512);
    u16*   wpb   = (u16*)(W + 117833728);
    u16*   w1b   = (u16*)(W + 118095872);
    u16*   w2b   = (u16*)(W + 118620160);

    prep_k<<<2048, 256, 0, stream>>>(x, xb, w_qkv, wqb, w_proj, wpb,
                                     w_mb1, w1b, w_mb2, w2b);
    gemm_bf<0><<<dim3(8, 6, 16), 256, 0, stream>>>(
        wqb, xb, nullptr, nullptr, nullptr, nullptr, qkvb, 768, 256);
    dwconv_k<5, 2, 768, false><<<dim3(16 * 768), 256, 0, stream>>>(
        qkvb, w_agg_dw, nullptr, dwb);
    gconv_k<<<dim3(96, 16), 256, 0, stream>>>(dwb, w_agg_pw, aggb);
    kv_k<<<dim3(1024), 64, 0, stream>>>(qkvb, aggb, kvp);
    attn_k<<<dim3(1024), 256, 0, stream>>>(qkvb, aggb, kvp, attnb);
    gemm_bf<2><<<dim3(8, 2, 16), 256, 0, stream>>>(
        wpb, attnb, bnp_s, bnp_b, x, y1f, y1b, 256, 512);
    gemm_bf<1><<<dim3(8, 8, 16), 256, 0, stream>>>(
        w1b, y1b, b_mb1, nullptr, nullptr, nullptr, h1b, 1024, 256);
    dwconv_k<3, 1, 1024, true><<<dim3(16 * 1024), 256, 0, stream>>>(
        h1b, w_mb_dw, b_mb_dw, h2b);
    gemm_bf<3><<<dim3(8, 2, 16), 256, 0, stream>>>(
        w2b, h2b, bn2_s, bn2_b, y1f, out, nullptr, 256, 1024);
}

// Round 3
// 261.567 us; speedup vs baseline: 3.3048x; 1.0295x over previous
//
#include <hip/hip_runtime.h>
#include <hip/hip_bf16.h>

// ---------------------------------------------------------------------------
// EfficientViT block (LiteMLA + MBConv), B=16, C=256, H=W=32.
// Round 2: GEMM rewrite — global_load_lds(16B) both sides with pre-swizzled
// global source (rule 21), no transpose staging; TM=64 2-wave blocks for
// M=256 GEMMs (2 blocks/CU). Non-GEMM kernels unchanged from round 1.
// Workspace (byte offsets, liveness-aliased):
//   [0        , 25165824) qkv_b          | h1_b = [0, 33554432)   (K6+)
//   [25165824 , 33554432) xb             |
//   [33554432 , 58720256) dw_b           | attn_b = [33554432, 50331648) (K4b+)
//   [58720256 , 83886080) agg_b          | h2_b = [58720256, 92274688)  (K7+)
//   [83886080 , 88211456) kvp            |
//   [92274688 ,109051904) y1f (fp32)
//   [109051904,117440512) y1b
//   [117440512,...      ) wq_b, wp_b, w1_b, w2_b (bf16 weights)
// ---------------------------------------------------------------------------

typedef unsigned short u16;
typedef __attribute__((ext_vector_type(8))) short short8;
typedef __attribute__((ext_vector_type(4))) short short4v;
typedef __attribute__((ext_vector_type(4))) float f32x4;

#define HW 1024
#define EPSV 1e-5f
#define MFMA16(a, b, c) __builtin_amdgcn_mfma_f32_16x16x32_bf16((a), (b), (c), 0, 0, 0)

__device__ __forceinline__ u16 f2bf(float f) {
    union { __hip_bfloat16 h; u16 u; } c; c.h = __float2bfloat16(f); return c.u;
}
__device__ __forceinline__ float bf2f(u16 u) {
    union { u16 u; __hip_bfloat16 h; } c; c.u = u; return __bfloat162float(c.h);
}
__device__ __forceinline__ float hswish(float v) {
    return v * fminf(fmaxf(v + 3.f, 0.f), 6.f) * (1.f / 6.f);
}
__device__ __forceinline__ void gload_lds16(const u16* g, u16* lds) {
    __builtin_amdgcn_global_load_lds(
        (const __attribute__((address_space(1))) void*)g,
        (__attribute__((address_space(3))) void*)lds, 16, 0, 0);
}

// ---------------- P0: fp32 -> bf16 casts ------------------------------------
__global__ __launch_bounds__(256) void prep_k(
    const float* __restrict__ x,  u16* __restrict__ xb,
    const float* __restrict__ wq, u16* __restrict__ wqb,
    const float* __restrict__ wp, u16* __restrict__ wpb,
    const float* __restrict__ w1, u16* __restrict__ w1b,
    const float* __restrict__ w2, u16* __restrict__ w2b)
{
    const int N0 = 4194304, N1 = 196608, N2 = 131072, N3 = 262144;
    const int total = N0 + N1 + N2 + N3 + 262144;
    for (int i = blockIdx.x * 256 + threadIdx.x; i < total; i += gridDim.x * 256) {
        int id = i;
        if (id < N0) { xb[id]  = f2bf(x[id]);  continue; } id -= N0;
        if (id < N1) { wqb[id] = f2bf(wq[id]); continue; } id -= N1;
        if (id < N2) { wpb[id] = f2bf(wp[id]); continue; } id -= N2;
        if (id < N3) { w1b[id] = f2bf(w1[id]); continue; } id -= N3;
        w2b[id] = f2bf(w2[id]);
    }
}

// ---------------- bf16 MFMA GEMM: C[b][m][n] = sum_k A[m][k]*Act[b][k][n] ---
// Tile TM x 128, BK=64, NW=TM/32 waves (each wave 64m x 64n).
// As[m][64k]: rows 128B, chunk idx c in [0,8), stored at c ^ (m&7).
// Bs[k][128n]: rows 256B (natural layout, NO transpose), chunk idx c in
// [0,16), stored at c ^ ((k>>3)&7).  Both staged via global_load_lds(16B)
// with the inverse swizzle applied to the GLOBAL source address (rule 21):
// within a row the sources permute inside one 128B/256B segment, so
// coalescing is preserved.  B-fragments are gathered as 8 x ds_read_u16 at
// stride 256B from one base (max 2-way bank aliasing, free).
// EPI 0: bf16   1: +bias,hswish,bf16   2: BN+res -> f32+bf16   3: BN+res -> f32
template<int EPI, int TM>
__global__ __launch_bounds__(TM * 2) void gemm_bf(
    const u16* __restrict__ A, const u16* __restrict__ Bact,
    const float* __restrict__ s1, const float* __restrict__ s2,
    const float* __restrict__ Rres, float* __restrict__ outF,
    u16* __restrict__ outB, int M, int K)
{
    constexpr int NW = TM / 32;                 // waves per block
    const int b  = blockIdx.z;
    const int n0 = blockIdx.x * 128;
    const int m0 = blockIdx.y * TM;
    const int t  = threadIdx.x;
    const int l  = t & 63, w = t >> 6;
    const int lr = t & 15, lg = (t >> 4) & 3;
    const int wm = (TM == 128) ? (w >> 1) : 0;
    const int wn = (TM == 128) ? (w & 1) : w;

    __shared__ __attribute__((aligned(16))) u16 As[TM * 64];
    __shared__ __attribute__((aligned(16))) u16 Bs[64 * 128];

    const u16* Ab0 = A + (size_t)m0 * K;
    const u16* Bp  = Bact + (size_t)b * K * HW + n0;

    f32x4 zero4 = {0.f, 0.f, 0.f, 0.f};
    f32x4 acc[4][4];
    #pragma unroll
    for (int i = 0; i < 4; ++i)
        #pragma unroll
        for (int j = 0; j < 4; ++j) acc[i][j] = zero4;

    for (int k0 = 0; k0 < K; k0 += 64) {
        #pragma unroll
        for (int u = 0; u < 4; ++u) {            // stage A: TM*8 chunks
            int g = (u * NW + w) * 64 + l;
            int row = g >> 3, cl = g & 7;
            int cs = cl ^ (row & 7);
            gload_lds16(Ab0 + (size_t)row * K + k0 + cs * 8,
                        As + (size_t)(u * NW + w) * 512);
        }
        #pragma unroll
        for (int u = 0; u < 16 / NW; ++u) {      // stage B: 1024 chunks
            int g = (u * NW + w) * 64 + l;
            int k = g >> 4, cl = g & 15;
            int cs = cl ^ ((k >> 3) & 7);
            gload_lds16(Bp + (size_t)(k0 + k) * HW + cs * 8,
                        Bs + (size_t)(u * NW + w) * 512);
        }
        __syncthreads();
        #pragma unroll
        for (int kk = 0; kk < 2; ++kk) {
            short8 a[4], bb[4];
            #pragma unroll
            for (int i = 0; i < 4; ++i) {
                int row = wm * 64 + i * 16 + lr;
                a[i] = *(const short8*)(&As[row * 64 + (((kk * 4 + lg) ^ (lr & 7)) * 8)]);
            }
            #pragma unroll
            for (int j = 0; j < 4; ++j) {
                int n = wn * 64 + j * 16 + lr;
                int c = (n >> 3) ^ ((kk * 4 + lg) & 7);
                const u16* bp = &Bs[(kk * 32 + lg * 8) * 128 + c * 8 + (n & 7)];
                short8 v;
                #pragma unroll
                for (int jj = 0; jj < 8; ++jj) v[jj] = (short)bp[(size_t)jj * 128];
                bb[j] = v;
            }
            #pragma unroll
            for (int i = 0; i < 4; ++i)
                #pragma unroll
                for (int j = 0; j < 4; ++j)
                    acc[i][j] = MFMA16(a[i], bb[j], acc[i][j]);
        }
        __syncthreads();
    }

    const size_t obase = (size_t)b * M * HW;
    #pragma unroll
    for (int i = 0; i < 4; ++i) {
        #pragma unroll
        for (int r = 0; r < 4; ++r) {
            const int grow = m0 + wm * 64 + i * 16 + lg * 4 + r;
            float p1 = 0.f, p2 = 0.f;
            if (EPI == 1) { p1 = s1[grow]; }
            if (EPI >= 2) { p1 = s1[grow]; p2 = s2[grow]; }
            #pragma unroll
            for (int j = 0; j < 4; ++j) {
                const int gcol = n0 + wn * 64 + j * 16 + lr;
                const size_t off = obase + (size_t)grow * HW + gcol;
                float v = acc[i][j][r];
                if (EPI == 0) { outB[off] = f2bf(v); }
                if (EPI == 1) { v = hswish(v + p1); outB[off] = f2bf(v); }
                if (EPI == 2) { v = v * p1 + p2 + Rres[off]; outF[off] = v; outB[off] = f2bf(v); }
                if (EPI == 3) { v = v * p1 + p2 + Rres[off]; outF[off] = v; }
            }
        }
    }
}

// ---------------- depthwise conv (bf16 io, fp32 math) -----------------------
template<int KS, int PAD, int NCH, bool HS>
__global__ __launch_bounds__(256) void dwconv_k(
    const u16* __restrict__ in, const float* __restrict__ w,
    const float* __restrict__ bias, u16* __restrict__ out)
{
    constexpr int T = 32 + 2 * PAD;
    __shared__ float tile[T * T];
    const int plane = blockIdx.x;
    const int c = plane % NCH;
    const u16* ip = in + (size_t)plane * HW;
    const int t = threadIdx.x;
    for (int idx = t; idx < T * T; idx += 256) {
        int r = idx / T, cc = idx % T;
        int gr = r - PAD, gc = cc - PAD;
        float v = 0.f;
        if ((unsigned)gr < 32u && (unsigned)gc < 32u) v = bf2f(ip[gr * 32 + gc]);
        tile[idx] = v;
    }
    float wl[KS * KS];
    #pragma unroll
    for (int u = 0; u < KS * KS; ++u) wl[u] = w[c * KS * KS + u];
    const float bv = HS ? bias[c] : 0.f;
    __syncthreads();
    #pragma unroll
    for (int pj = 0; pj < 4; ++pj) {
        const int px = t + pj * 256;
        const int pr = px >> 5, pc = px & 31;
        float s = bv;
        #pragma unroll
        for (int dr = 0; dr < KS; ++dr)
            #pragma unroll
            for (int dc = 0; dc < KS; ++dc)
                s += tile[(pr + dr) * T + pc + dc] * wl[dr * KS + dc];
        if (HS) s = hswish(s);
        out[(size_t)plane * HW + px] = f2bf(s);
    }
}

// ---------------- grouped 1x1 (24 groups of 32->32), bf16 io ----------------
__global__ __launch_bounds__(256) void gconv_k(
    const u16* __restrict__ dw, const float* __restrict__ wpw,
    u16* __restrict__ agg)
{
    const int gx = blockIdx.x;               // g*4 + ntile
    const int g = gx >> 2, nt = gx & 3;
    const int b = blockIdx.y;
    const int n0 = nt * 256;
    const int t = threadIdx.x;
    __shared__ float dt[32][256];
    __shared__ float wl[32 * 32];
    const u16* dp = dw + ((size_t)b * 768 + g * 32) * HW + n0;
    for (int idx = t; idx < 32 * 256; idx += 256) {
        int i = idx >> 8, nn = idx & 255;
        dt[i][nn] = bf2f(dp[(size_t)i * HW + nn]);
    }
    for (int idx = t; idx < 1024; idx += 256) wl[idx] = wpw[g * 1024 + idx];
    __syncthreads();
    float acc[32] = {};
    #pragma unroll
    for (int i = 0; i < 32; ++i) {
        const float d = dt[i][t];
        #pragma unroll
        for (int oc = 0; oc < 32; ++oc) acc[oc] += wl[oc * 32 + i] * d;
    }
    u16* ap = agg + ((size_t)b * 768 + g * 32) * HW + n0;
    #pragma unroll
    for (int oc = 0; oc < 32; ++oc) ap[(size_t)oc * HW + t] = f2bf(acc[oc]);
}

// ---------------- K4a: kv partials via MFMA, zero LDS -----------------------
__global__ __launch_bounds__(64) void kv_k(
    const u16* __restrict__ qkvb, const u16* __restrict__ aggb,
    float* __restrict__ kvp)
{
    const int blk = blockIdx.x;              // bh*4 + nc
    const int bh = blk >> 2, nc = blk & 3;
    const int b = bh >> 4, h = bh & 15;
    const u16* src = (h < 8) ? qkvb + ((size_t)b * 768 + h * 96) * HW
                             : aggb + ((size_t)b * 768 + (h - 8) * 96) * HW;
    const u16* kp = src + 32 * HW + nc * 256;
    const u16* vp = src + 64 * HW + nc * 256;
    const int l = threadIdx.x;
    const int lr = l & 15, lg = l >> 4;

    f32x4 zero4 = {0.f, 0.f, 0.f, 0.f};
    f32x4 acc[2][3];
    #pragma unroll
    for (int i = 0; i < 2; ++i)
        #pragma unroll
        for (int j = 0; j < 3; ++j) acc[i][j] = zero4;

    short8 bones;
    #pragma unroll
    for (int g = 0; g < 8; ++g) bones[g] = (lr == 0) ? (short)0x3F80 : (short)0;

    for (int ks = 0; ks < 8; ++ks) {
        const int kn = ks * 32 + lg * 8;
        short8 a0 = *(const short8*)(kp + (size_t)lr * HW + kn);
        short8 a1 = *(const short8*)(kp + (size_t)(16 + lr) * HW + kn);
        #pragma unroll
        for (int g = 0; g < 8; ++g) {     // relu on bf16 bits
            if (((u16)a0[g]) & 0x8000) a0[g] = 0;
            if (((u16)a1[g]) & 0x8000) a1[g] = 0;
        }
        short8 b0 = *(const short8*)(vp + (size_t)lr * HW + kn);
        short8 b1 = *(const short8*)(vp + (size_t)(16 + lr) * HW + kn);
        acc[0][0] = MFMA16(a0, b0, acc[0][0]);
        acc[0][1] = MFMA16(a0, b1, acc[0][1]);
        acc[0][2] = MFMA16(a0, bones, acc[0][2]);
        acc[1][0] = MFMA16(a1, b0, acc[1][0]);
        acc[1][1] = MFMA16(a1, b1, acc[1][1]);
        acc[1][2] = MFMA16(a1, bones, acc[1][2]);
    }
    float* dst = kvp + (size_t)blk * 1056;
    #pragma unroll
    for (int dt = 0; dt < 2; ++dt)
        #pragma unroll
        for (int et = 0; et < 3; ++et)
            #pragma unroll
            for (int r = 0; r < 4; ++r) {
                const int d = dt * 16 + lg * 4 + r;
                const int e = et * 16 + lr;
                if (et < 2 || lr == 0) dst[d * 33 + e] = acc[dt][et][r];
            }
}

// ---------------- K4b: attn = normalize(relu(Q) @ kv) via MFMA --------------
__global__ __launch_bounds__(256) void attn_k(
    const u16* __restrict__ qkvb, const u16* __restrict__ aggb,
    const float* __restrict__ kvp, u16* __restrict__ attnb)
{
    const int blk = blockIdx.x;
    const int bh = blk >> 2, nc = blk & 3;
    const int b = bh >> 4, h = bh & 15;
    const u16* qp = (h < 8) ? qkvb + ((size_t)b * 768 + h * 96) * HW
                            : aggb + ((size_t)b * 768 + (h - 8) * 96) * HW;
    __shared__ u16 qs[256 * 40];
    const int t = threadIdx.x;
    #pragma unroll 4
    for (int u = 0; u < 32; ++u) {           // stage Q^T with relu
        int id = t + u * 256;                // 8192 elems
        int d = id >> 8, n = id & 255;
        u16 q = qp[(size_t)d * HW + nc * 256 + n];
        if (q & 0x8000) q = 0;
        qs[n * 40 + d] = q;
    }
    const int lr = t & 15, lg = (t >> 4) & 3, w = t >> 6;

    short8 bf[3];                            // kv as B-frags (sum 4 partials)
    const float* kb = kvp + (size_t)bh * 4 * 1056;
    #pragma unroll
    for (int et = 0; et < 3; ++et)
        #pragma unroll
        for (int j = 0; j < 8; ++j) {
            const int d = lg * 8 + j, e = et * 16 + lr;
            float s = 0.f;
            if (e <= 32) {
                #pragma unroll
                for (int c = 0; c < 4; ++c) s += kb[c * 1056 + d * 33 + e];
            }
            bf[et][j] = (short)f2bf(s);
        }
    __syncthreads();

    f32x4 zero4 = {0.f, 0.f, 0.f, 0.f};
    f32x4 acc[4][3];
    #pragma unroll
    for (int i = 0; i < 4; ++i) {
        const int row = w * 64 + i * 16 + lr;
        short8 a = *(const short8*)(&qs[row * 40 + lg * 8]);
        #pragma unroll
        for (int et = 0; et < 3; ++et) acc[i][et] = MFMA16(a, bf[et], zero4);
    }

    u16* ap = attnb + (size_t)b * 512 * HW + (size_t)h * 32 * HW;
    #pragma unroll
    for (int i = 0; i < 4; ++i) {
        float inv[4];
        #pragma unroll
        for (int r = 0; r < 4; ++r) {
            const float den = __shfl(acc[i][2][r], t & 48, 64);
            inv[r] = 1.f / (den + EPSV);
        }
        const int nbase = nc * 256 + w * 64 + i * 16 + lg * 4;
        #pragma unroll
        for (int et = 0; et < 2; ++et) {
            const int e = et * 16 + lr;
            short4v o;
            #pragma unroll
            for (int r = 0; r < 4; ++r) o[r] = (short)f2bf(acc[i][et][r] * inv[r]);
            *(short4v*)(ap + (size_t)e * HW + nbase) = o;
        }
    }
}

// ---------------------------------------------------------------------------
extern "C" void kernel_launch(void* const* d_in, const int* in_sizes, int n_in,
                              void* d_out, int out_size, void* d_ws, size_t ws_size,
                              hipStream_t stream)
{
    const float* x        = (const float*)d_in[0];
    const float* w_qkv    = (const float*)d_in[1];
    const float* w_agg_dw = (const float*)d_in[2];
    const float* w_agg_pw = (const float*)d_in[3];
    const float* w_proj   = (const float*)d_in[4];
    const float* bnp_s    = (const float*)d_in[5];
    const float* bnp_b    = (const float*)d_in[6];
    const float* w_mb1    = (const float*)d_in[7];
    const float* b_mb1    = (const float*)d_in[8];
    const float* w_mb_dw  = (const float*)d_in[9];
    const float* b_mb_dw  = (const float*)d_in[10];
    const float* w_mb2    = (const float*)d_in[11];
    const float* bn2_s    = (const float*)d_in[12];
    const float* bn2_b    = (const float*)d_in[13];
    float* out = (float*)d_out;
    char*  W   = (char*)d_ws;

    u16*   qkvb  = (u16*)(W + 0);
    u16*   xb    = (u16*)(W + 25165824);
    u16*   dwb   = (u16*)(W + 33554432);
    u16*   aggb  = (u16*)(W + 58720256);
    float* kvp   = (float*)(W + 83886080);
    u16*   attnb = (u16*)(W + 33554432);     // alias: dwb dead after gconv
    u16*   h1b   = (u16*)(W + 0);            // alias: qkvb+xb dead after attn
    u16*   h2b   = (u16*)(W + 58720256);     // alias: aggb+kvp dead after attn
    float* y1f   = (float*)(W + 92274688);
    u16*   y1b   = (u16*)(W + 109051904);
    u16*   wqb   = (u16*)(W + 117440512);
    u16*   wpb   = (u16*)(W + 117833728);
    u16*   w1b   = (u16*)(W + 118095872);
    u16*   w2b   = (u16*)(W + 118620160);

    prep_k<<<2048, 256, 0, stream>>>(x, xb, w_qkv, wqb, w_proj, wpb,
                                     w_mb1, w1b, w_mb2, w2b);
    gemm_bf<0, 128><<<dim3(8, 6, 16), 256, 0, stream>>>(
        wqb, xb, nullptr, nullptr, nullptr, nullptr, qkvb, 768, 256);
    dwconv_k<5, 2, 768, false><<<dim3(16 * 768), 256, 0, stream>>>(
        qkvb, w_agg_dw, nullptr, dwb);
    gconv_k<<<dim3(96, 16), 256, 0, stream>>>(dwb, w_agg_pw, aggb);
    kv_k<<<dim3(1024), 64, 0, stream>>>(qkvb, aggb, kvp);
    attn_k<<<dim3(1024), 256, 0, stream>>>(qkvb, aggb, kvp, attnb);
    gemm_bf<2, 64><<<dim3(8, 4, 16), 128, 0, stream>>>(
        wpb, attnb, bnp_s, bnp_b, x, y1f, y1b, 256, 512);
    gemm_bf<1, 128><<<dim3(8, 8, 16), 256, 0, stream>>>(
        w1b, y1b, b_mb1, nullptr, nullptr, nullptr, h1b, 1024, 256);
    dwconv_k<3, 1, 1024, true><<<dim3(16 * 1024), 256, 0, stream>>>(
        h1b, w_mb_dw, b_mb_dw, h2b);
    gemm_bf<3, 64><<<dim3(8, 4, 16), 128, 0, stream>>>(
        w2b, h2b, bn2_s, bn2_b, y1f, out, nullptr, 256, 1024);
}